// Round 18
// baseline (189.180 us; speedup 1.0000x reference)
//
#include <hip/hip_runtime.h>

#define NN 10000
#define NE 160000
#define DM 256
#define CAP 96
#define LN_EPSF 1e-5f
#define SCALEF 0.17677669529663687f  // 1/sqrt(32)

typedef unsigned short u16;
typedef __attribute__((ext_vector_type(4))) u16 u16x4;
typedef __attribute__((ext_vector_type(8))) u16 u16x8;
typedef __attribute__((ext_vector_type(4))) float f32x4;
typedef __attribute__((ext_vector_type(8))) short short8;

__device__ __forceinline__ float b2f(u16 u) { return __uint_as_float(((unsigned)u) << 16); }
__device__ __forceinline__ u16 f2b(float f) {
    unsigned u = __float_as_uint(f);
    return (u16)((u + 0x7fffu + ((u >> 16) & 1u)) >> 16);
}
__device__ __forceinline__ int clampi(int v) { return v < 0 ? 0 : (v >= NN ? NN - 1 : v); }

__global__ void k_fill_zero_f32(float* __restrict__ o, int n) {
    int i = blockIdx.x * 256 + threadIdx.x;
    if (i < n) o[i] = 0.f;
}

// ---------------- prep: W transpose+bf16 (Wt[m][n][k]) AND zero degree counters ----------------
__global__ void k_prep(const float* __restrict__ Wq, const float* __restrict__ Wk,
                       const float* __restrict__ Wv, const float* __restrict__ Wo,
                       u16* __restrict__ Wt, int* __restrict__ cnt) {
    int id = blockIdx.x * 256 + threadIdx.x;   // 0..262143
    if (id < NN) cnt[id] = 0;
    int m = id >> 16;
    int rc = id & 65535;
    int r = rc >> 8, c = rc & 255;
    const float* W = (m == 0) ? Wq : (m == 1) ? Wk : (m == 2) ? Wv : Wo;
    Wt[m * 65536 + c * 256 + r] = f2b(W[r * 256 + c]);
}

// ---------------- fused dispatch: y<3 = QKV GEMM (direct-load MFMA), y==3 = bucket scatter ----
// GEMM: no LDS. A frag = contiguous 16B of X row (fp32->bf16); B frag = contiguous 16B of Wt row.
// KV layout: KV[node*512 + (col>>2)*8 + (col&3) (+4 for V)]
__global__ __launch_bounds__(256) void k_qkv_bucket(const float* __restrict__ X, const u16* __restrict__ Wt,
                                                    u16* __restrict__ Q, u16* __restrict__ KV,
                                                    const int* __restrict__ EI, int* __restrict__ cnt,
                                                    int* __restrict__ buck) {
    if (blockIdx.y == 3) {
        int e = blockIdx.x * 256 + threadIdx.x;
        if (e < NE) {
            int s = clampi(EI[e]);
            int slot = atomicAdd(&cnt[s], 1);
            if (slot < CAP) buck[s * CAP + slot] = clampi(EI[NE + e]);
        }
        return;
    }
    if (blockIdx.x >= 157) return;
    const int t = threadIdx.x;
    const int w = t >> 6, l = t & 63, quad = l >> 4, m16 = l & 15;
    const int mat = blockIdx.y;
    const u16* Wm = Wt + mat * 65536;
    const int node0 = blockIdx.x * 64;
    const int arow = node0 + w * 16 + m16;   // A-operand row for this lane
    f32x4 acc[16];
#pragma unroll
    for (int i = 0; i < 16; i++) acc[i] = (f32x4){0.f, 0.f, 0.f, 0.f};
#pragma unroll
    for (int k0 = 0; k0 < DM; k0 += 32) {
        short8 a = {0, 0, 0, 0, 0, 0, 0, 0};
        if (arow < NN) {
            const float* xp = X + (size_t)arow * DM + k0 + quad * 8;
            f32x4 a0 = *(const f32x4*)(xp);
            f32x4 a1 = *(const f32x4*)(xp + 4);
            a[0] = (short)f2b(a0[0]); a[1] = (short)f2b(a0[1]);
            a[2] = (short)f2b(a0[2]); a[3] = (short)f2b(a0[3]);
            a[4] = (short)f2b(a1[0]); a[5] = (short)f2b(a1[1]);
            a[6] = (short)f2b(a1[2]); a[7] = (short)f2b(a1[3]);
        }
#pragma unroll
        for (int ct = 0; ct < 16; ct++) {
            short8 b = *(const short8*)(Wm + (ct * 16 + m16) * DM + k0 + quad * 8);
            acc[ct] = __builtin_amdgcn_mfma_f32_16x16x32_bf16(a, b, acc[ct], 0, 0, 0);
        }
    }
#pragma unroll
    for (int ct = 0; ct < 16; ct++) {
        int col = ct * 16 + m16;
#pragma unroll
        for (int r = 0; r < 4; r++) {
            int node = node0 + w * 16 + quad * 4 + r;
            if (node < NN) {
                u16 v = f2b(acc[ct][r]);
                if (mat == 0) Q[(size_t)node * DM + col] = v;
                else KV[(size_t)node * 512 + (col >> 2) * 8 + (col & 3) + ((mat == 2) ? 4 : 0)] = v;
            }
        }
    }
}

// ---------------- edge attention: one wave per src node, bucket list, online softmax ----------------
__global__ __launch_bounds__(256) void k_edge(const u16* __restrict__ Q, const u16* __restrict__ KV,
                                              const int* __restrict__ cnt, const int* __restrict__ buck,
                                              u16* __restrict__ attn) {
    const int t = threadIdx.x;
    const int w = t >> 6, l = t & 63;
    const int node = blockIdx.x * 4 + w;
    const int d0 = l * 4;
    int deg = cnt[node];
    if (deg > CAP) deg = CAP;
    const int* bl = buck + node * CAP;
    u16x4 q4 = *(const u16x4*)(Q + (size_t)node * DM + d0);
    float qf0 = b2f(q4[0]) * SCALEF, qf1 = b2f(q4[1]) * SCALEF;
    float qf2 = b2f(q4[2]) * SCALEF, qf3 = b2f(q4[3]) * SCALEF;
    float m = -3.0e38f, s = 0.f;
    float a0 = 0.f, a1 = 0.f, a2 = 0.f, a3 = 0.f;
    for (int i = 0; i < deg; i++) {
        int dst = bl[i];
        u16x8 kv = *(const u16x8*)(KV + (size_t)dst * 512 + l * 8);
        float p = qf0 * b2f(kv[0]) + qf1 * b2f(kv[1]) + qf2 * b2f(kv[2]) + qf3 * b2f(kv[3]);
        p += __shfl_xor(p, 1, 64);
        p += __shfl_xor(p, 2, 64);
        p += __shfl_xor(p, 4, 64);
        float nm = fmaxf(m, p);
        float al = __expf(m - nm);
        float pe = __expf(p - nm);
        s = s * al + pe;
        a0 = a0 * al + pe * b2f(kv[4]);
        a1 = a1 * al + pe * b2f(kv[5]);
        a2 = a2 * al + pe * b2f(kv[6]);
        a3 = a3 * al + pe * b2f(kv[7]);
        m = nm;
    }
    float inv = (s > 0.f) ? 1.f / s : 0.f;
    u16x4 o;
    o[0] = f2b(a0 * inv);
    o[1] = f2b(a1 * inv);
    o[2] = f2b(a2 * inv);
    o[3] = f2b(a3 * inv);
    *(u16x4*)(attn + (size_t)node * DM + d0) = o;
}

// ---------------- out-proj GEMM (direct-load MFMA) + residual + LayerNorm fused ----------------
__global__ __launch_bounds__(256) void k_gemm_out_ln(const u16* __restrict__ In, const u16* __restrict__ WoT,
                                                     const float* __restrict__ X, const float* __restrict__ g,
                                                     const float* __restrict__ b, float* __restrict__ out) {
    __shared__ float gl[256], bl[256];
    const int t = threadIdx.x;
    gl[t] = g[t];
    bl[t] = b[t];
    __syncthreads();
    const int w = t >> 6, l = t & 63, quad = l >> 4, m16 = l & 15;
    const int node0 = blockIdx.x * 64;
    const int arow = node0 + w * 16 + m16;
    f32x4 acc[16];
#pragma unroll
    for (int i = 0; i < 16; i++) acc[i] = (f32x4){0.f, 0.f, 0.f, 0.f};
#pragma unroll
    for (int k0 = 0; k0 < DM; k0 += 32) {
        short8 a = {0, 0, 0, 0, 0, 0, 0, 0};
        if (arow < NN) a = *(const short8*)(In + (size_t)arow * DM + k0 + quad * 8);
#pragma unroll
        for (int ct = 0; ct < 16; ct++) {
            short8 bfr = *(const short8*)(WoT + (ct * 16 + m16) * DM + k0 + quad * 8);
            acc[ct] = __builtin_amdgcn_mfma_f32_16x16x32_bf16(a, bfr, acc[ct], 0, 0, 0);
        }
    }
    float val[16][4];
    const int nodeBase = node0 + w * 16 + quad * 4;
#pragma unroll
    for (int ct = 0; ct < 16; ct++) {
        int col = ct * 16 + m16;
#pragma unroll
        for (int r = 0; r < 4; r++) {
            int node = nodeBase + r;
            float x = (node < NN) ? X[(size_t)node * DM + col] : 0.f;
            val[ct][r] = acc[ct][r] + x;
        }
    }
    float mu[4], rstd[4];
#pragma unroll
    for (int r = 0; r < 4; r++) {
        float s1 = 0.f, s2 = 0.f;
#pragma unroll
        for (int ct = 0; ct < 16; ct++) {
            float v = val[ct][r];
            s1 += v;
            s2 += v * v;
        }
#pragma unroll
        for (int o = 1; o < 16; o <<= 1) {
            s1 += __shfl_xor(s1, o, 64);
            s2 += __shfl_xor(s2, o, 64);
        }
        float mm = s1 * (1.f / DM);
        float var = s2 * (1.f / DM) - mm * mm;
        mu[r] = mm;
        rstd[r] = rsqrtf(var + LN_EPSF);
    }
#pragma unroll
    for (int ct = 0; ct < 16; ct++) {
        int col = ct * 16 + m16;
#pragma unroll
        for (int r = 0; r < 4; r++) {
            int node = nodeBase + r;
            if (node < NN)
                out[(size_t)node * DM + col] = (val[ct][r] - mu[r]) * rstd[r] * gl[col] + bl[col];
        }
    }
}

extern "C" void kernel_launch(void* const* d_in, const int* in_sizes, int n_in,
                              void* d_out, int out_size, void* d_ws, size_t ws_size,
                              hipStream_t stream) {
    (void)in_sizes; (void)n_in;
    const float* X  = (const float*)d_in[0];
    const int*   EI = (const int*)d_in[1];
    const float* Wq = (const float*)d_in[2];
    const float* Wk = (const float*)d_in[3];
    const float* Wv = (const float*)d_in[4];
    const float* Wo = (const float*)d_in[5];
    const float* g  = (const float*)d_in[6];
    const float* be = (const float*)d_in[7];

    // ws: Wt 512K | KV 10M | attn 5M | cnt 40K | buck 3.84M  (~19.6 MB)
    const size_t SWT  = (size_t)4 * 65536 * 2;
    const size_t SKV  = (size_t)NN * 512 * 2;
    const size_t SAT  = (size_t)NN * DM * 2;
    const size_t SCNT = (size_t)NN * 4;
    const size_t SBK  = (size_t)NN * CAP * 4;
    const size_t need = SWT + SKV + SAT + SCNT + SBK;
    if (ws_size < need) {
        k_fill_zero_f32<<<(out_size + 255) / 256, 256, 0, stream>>>((float*)d_out, out_size);
        return;
    }
    char* p = (char*)d_ws;
    u16* Wt   = (u16*)p; p += SWT;
    u16* KVb  = (u16*)p; p += SKV;
    u16* attn = (u16*)p; p += SAT;
    int* cnt  = (int*)p; p += SCNT;
    int* buck = (int*)p; p += SBK;
    u16* Qb = (u16*)d_out;  // Q staged in d_out lower half (dead before k_gemm_out_ln writes)

    k_prep<<<1024, 256, 0, stream>>>(Wq, Wk, Wv, Wo, Wt, cnt);
    k_qkv_bucket<<<dim3(625, 4), 256, 0, stream>>>(X, Wt, Qb, KVb, EI, cnt, buck);
    k_edge<<<NN / 4, 256, 0, stream>>>(Qb, KVb, cnt, buck, attn);
    k_gemm_out_ln<<<157, 256, 0, stream>>>(attn, Wt + 3 * 65536, X, g, be, (float*)d_out);
}

// Round 19
// 150.943 us; speedup vs baseline: 1.2533x; 1.2533x over previous
//
#include <hip/hip_runtime.h>

#define NN 10000
#define NE 160000
#define DM 256
#define CAP 96
#define LN_EPSF 1e-5f
#define SCALEF 0.17677669529663687f  // 1/sqrt(32)

typedef unsigned short u16;
typedef __attribute__((ext_vector_type(4))) u16 u16x4;
typedef __attribute__((ext_vector_type(8))) u16 u16x8;
typedef __attribute__((ext_vector_type(4))) float f32x4;
typedef __attribute__((ext_vector_type(8))) short short8;

__device__ __forceinline__ float b2f(u16 u) { return __uint_as_float(((unsigned)u) << 16); }
__device__ __forceinline__ u16 f2b(float f) {
    unsigned u = __float_as_uint(f);
    return (u16)((u + 0x7fffu + ((u >> 16) & 1u)) >> 16);
}
__device__ __forceinline__ int clampi(int v) { return v < 0 ? 0 : (v >= NN ? NN - 1 : v); }

__global__ void k_fill_zero_f32(float* __restrict__ o, int n) {
    int i = blockIdx.x * 256 + threadIdx.x;
    if (i < n) o[i] = 0.f;
}

// ---------------- prep: W transpose+bf16 (Wt[m][n][k]) AND zero degree counters ----------------
__global__ void k_prep(const float* __restrict__ Wq, const float* __restrict__ Wk,
                       const float* __restrict__ Wv, const float* __restrict__ Wo,
                       u16* __restrict__ Wt, int* __restrict__ cnt) {
    int id = blockIdx.x * 256 + threadIdx.x;   // 0..262143
    if (id < NN) cnt[id] = 0;
    int m = id >> 16;
    int rc = id & 65535;
    int r = rc >> 8, c = rc & 255;
    const float* W = (m == 0) ? Wq : (m == 1) ? Wk : (m == 2) ? Wv : Wo;
    Wt[m * 65536 + c * 256 + r] = f2b(W[r * 256 + c]);
}

// ---------------- fused dispatch: y<3 = QKV GEMM (LDS-staged MFMA), y==3 = bucket scatter ----
// KV layout: KV[node*512 + (col>>2)*8 + (col&3) (+4 for V)]
__global__ __launch_bounds__(256) void k_qkv_bucket(const float* __restrict__ X, const u16* __restrict__ Wt,
                                                    u16* __restrict__ Q, u16* __restrict__ KV,
                                                    const int* __restrict__ EI, int* __restrict__ cnt,
                                                    int* __restrict__ buck) {
    constexpr int AS = 40;  // padded LDS row stride (u16): 80B = 20-bank stride
    __shared__ u16 At[64 * AS];
    __shared__ u16 Bt[256 * AS];
    if (blockIdx.y == 3) {
        int e = blockIdx.x * 256 + threadIdx.x;
        if (e < NE) {
            int s = clampi(EI[e]);
            int slot = atomicAdd(&cnt[s], 1);
            if (slot < CAP) buck[s * CAP + slot] = clampi(EI[NE + e]);
        }
        return;
    }
    if (blockIdx.x >= 157) return;
    const int t = threadIdx.x;
    const int w = t >> 6, l = t & 63, quad = l >> 4, m16 = l & 15;
    const int mat = blockIdx.y;
    const u16* Wm = Wt + mat * 65536;
    const int node0 = blockIdx.x * 64;
    f32x4 acc[16];
#pragma unroll
    for (int i = 0; i < 16; i++) acc[i] = (f32x4){0.f, 0.f, 0.f, 0.f};
    const int arow = t >> 2, ac8 = (t & 3) * 8;
    for (int k0 = 0; k0 < DM; k0 += 32) {
        u16x8 av = {0, 0, 0, 0, 0, 0, 0, 0};
        int anode = node0 + arow;
        if (anode < NN) {
            const float* xp = X + (size_t)anode * DM + k0 + ac8;
            f32x4 a0 = *(const f32x4*)(xp);
            f32x4 a1 = *(const f32x4*)(xp + 4);
            av[0] = f2b(a0[0]); av[1] = f2b(a0[1]); av[2] = f2b(a0[2]); av[3] = f2b(a0[3]);
            av[4] = f2b(a1[0]); av[5] = f2b(a1[1]); av[6] = f2b(a1[2]); av[7] = f2b(a1[3]);
        }
        *(u16x8*)(At + arow * AS + ac8) = av;
        const u16* bsrc = Wm + t * DM + k0;
        u16x8 b0 = *(const u16x8*)(bsrc);
        u16x8 b1 = *(const u16x8*)(bsrc + 8);
        u16x8 b2 = *(const u16x8*)(bsrc + 16);
        u16x8 b3 = *(const u16x8*)(bsrc + 24);
        u16* bd = Bt + t * AS;
        *(u16x8*)(bd) = b0;
        *(u16x8*)(bd + 8) = b1;
        *(u16x8*)(bd + 16) = b2;
        *(u16x8*)(bd + 24) = b3;
        __syncthreads();
        short8 a = *(const short8*)(At + (w * 16 + m16) * AS + quad * 8);
#pragma unroll
        for (int ct = 0; ct < 16; ct++) {
            short8 b = *(const short8*)(Bt + (ct * 16 + m16) * AS + quad * 8);
            acc[ct] = __builtin_amdgcn_mfma_f32_16x16x32_bf16(a, b, acc[ct], 0, 0, 0);
        }
        __syncthreads();
    }
#pragma unroll
    for (int ct = 0; ct < 16; ct++) {
        int col = ct * 16 + m16;
#pragma unroll
        for (int r = 0; r < 4; r++) {
            int node = node0 + w * 16 + quad * 4 + r;
            if (node < NN) {
                u16 v = f2b(acc[ct][r]);
                if (mat == 0) Q[(size_t)node * DM + col] = v;
                else KV[(size_t)node * 512 + (col >> 2) * 8 + (col & 3) + ((mat == 2) ? 4 : 0)] = v;
            }
        }
    }
}

// ---------------- edge attention: one wave per src node, bucket list, online softmax ----------------
__global__ __launch_bounds__(256) void k_edge(const u16* __restrict__ Q, const u16* __restrict__ KV,
                                              const int* __restrict__ cnt, const int* __restrict__ buck,
                                              u16* __restrict__ attn) {
    const int t = threadIdx.x;
    const int w = t >> 6, l = t & 63;
    const int node = blockIdx.x * 4 + w;
    const int d0 = l * 4;
    int deg = cnt[node];
    if (deg > CAP) deg = CAP;
    const int* bl = buck + node * CAP;
    u16x4 q4 = *(const u16x4*)(Q + (size_t)node * DM + d0);
    float qf0 = b2f(q4[0]) * SCALEF, qf1 = b2f(q4[1]) * SCALEF;
    float qf2 = b2f(q4[2]) * SCALEF, qf3 = b2f(q4[3]) * SCALEF;
    float m = -3.0e38f, s = 0.f;
    float a0 = 0.f, a1 = 0.f, a2 = 0.f, a3 = 0.f;
    for (int i = 0; i < deg; i++) {
        int dst = bl[i];
        u16x8 kv = *(const u16x8*)(KV + (size_t)dst * 512 + l * 8);
        float p = qf0 * b2f(kv[0]) + qf1 * b2f(kv[1]) + qf2 * b2f(kv[2]) + qf3 * b2f(kv[3]);
        p += __shfl_xor(p, 1, 64);
        p += __shfl_xor(p, 2, 64);
        p += __shfl_xor(p, 4, 64);
        float nm = fmaxf(m, p);
        float al = __expf(m - nm);
        float pe = __expf(p - nm);
        s = s * al + pe;
        a0 = a0 * al + pe * b2f(kv[4]);
        a1 = a1 * al + pe * b2f(kv[5]);
        a2 = a2 * al + pe * b2f(kv[6]);
        a3 = a3 * al + pe * b2f(kv[7]);
        m = nm;
    }
    float inv = (s > 0.f) ? 1.f / s : 0.f;
    u16x4 o;
    o[0] = f2b(a0 * inv);
    o[1] = f2b(a1 * inv);
    o[2] = f2b(a2 * inv);
    o[3] = f2b(a3 * inv);
    *(u16x4*)(attn + (size_t)node * DM + d0) = o;
}

// ---------------- out-proj GEMM (LDS-staged MFMA) + residual + LayerNorm fused ----------------
__global__ __launch_bounds__(256) void k_gemm_out_ln(const u16* __restrict__ In, const u16* __restrict__ WoT,
                                                     const float* __restrict__ X, const float* __restrict__ g,
                                                     const float* __restrict__ b, float* __restrict__ out) {
    constexpr int AS = 40;
    __shared__ u16 At[64 * AS];
    __shared__ u16 Bt[256 * AS];
    __shared__ float gl[256], bl[256];
    const int t = threadIdx.x;
    gl[t] = g[t];
    bl[t] = b[t];
    const int w = t >> 6, l = t & 63, quad = l >> 4, m16 = l & 15;
    const int node0 = blockIdx.x * 64;
    f32x4 acc[16];
#pragma unroll
    for (int i = 0; i < 16; i++) acc[i] = (f32x4){0.f, 0.f, 0.f, 0.f};
    const int arow = t >> 2, ac8 = (t & 3) * 8;
    for (int k0 = 0; k0 < DM; k0 += 32) {
        u16x8 av = {0, 0, 0, 0, 0, 0, 0, 0};
        int anode = node0 + arow;
        if (anode < NN) av = *(const u16x8*)(In + (size_t)anode * DM + k0 + ac8);
        *(u16x8*)(At + arow * AS + ac8) = av;
        const u16* bsrc = WoT + t * DM + k0;
        u16x8 b0 = *(const u16x8*)(bsrc);
        u16x8 b1 = *(const u16x8*)(bsrc + 8);
        u16x8 b2 = *(const u16x8*)(bsrc + 16);
        u16x8 b3 = *(const u16x8*)(bsrc + 24);
        u16* bd = Bt + t * AS;
        *(u16x8*)(bd) = b0;
        *(u16x8*)(bd + 8) = b1;
        *(u16x8*)(bd + 16) = b2;
        *(u16x8*)(bd + 24) = b3;
        __syncthreads();
        short8 a = *(const short8*)(At + (w * 16 + m16) * AS + quad * 8);
#pragma unroll
        for (int ct = 0; ct < 16; ct++) {
            short8 bfr = *(const short8*)(Bt + (ct * 16 + m16) * AS + quad * 8);
            acc[ct] = __builtin_amdgcn_mfma_f32_16x16x32_bf16(a, bfr, acc[ct], 0, 0, 0);
        }
        __syncthreads();
    }
    float val[16][4];
    const int nodeBase = node0 + w * 16 + quad * 4;
#pragma unroll
    for (int ct = 0; ct < 16; ct++) {
        int col = ct * 16 + m16;
#pragma unroll
        for (int r = 0; r < 4; r++) {
            int node = nodeBase + r;
            float x = (node < NN) ? X[(size_t)node * DM + col] : 0.f;
            val[ct][r] = acc[ct][r] + x;
        }
    }
    float mu[4], rstd[4];
#pragma unroll
    for (int r = 0; r < 4; r++) {
        float s1 = 0.f, s2 = 0.f;
#pragma unroll
        for (int ct = 0; ct < 16; ct++) {
            float v = val[ct][r];
            s1 += v;
            s2 += v * v;
        }
#pragma unroll
        for (int o = 1; o < 16; o <<= 1) {
            s1 += __shfl_xor(s1, o, 64);
            s2 += __shfl_xor(s2, o, 64);
        }
        float mm = s1 * (1.f / DM);
        float var = s2 * (1.f / DM) - mm * mm;
        mu[r] = mm;
        rstd[r] = rsqrtf(var + LN_EPSF);
    }
#pragma unroll
    for (int ct = 0; ct < 16; ct++) {
        int col = ct * 16 + m16;
#pragma unroll
        for (int r = 0; r < 4; r++) {
            int node = nodeBase + r;
            if (node < NN)
                out[(size_t)node * DM + col] = (val[ct][r] - mu[r]) * rstd[r] * gl[col] + bl[col];
        }
    }
}

extern "C" void kernel_launch(void* const* d_in, const int* in_sizes, int n_in,
                              void* d_out, int out_size, void* d_ws, size_t ws_size,
                              hipStream_t stream) {
    (void)in_sizes; (void)n_in;
    const float* X  = (const float*)d_in[0];
    const int*   EI = (const int*)d_in[1];
    const float* Wq = (const float*)d_in[2];
    const float* Wk = (const float*)d_in[3];
    const float* Wv = (const float*)d_in[4];
    const float* Wo = (const float*)d_in[5];
    const float* g  = (const float*)d_in[6];
    const float* be = (const float*)d_in[7];

    // ws: Wt 512K | KV 10M | attn 5M | cnt 40K | buck 3.84M  (~19.6 MB)
    const size_t SWT  = (size_t)4 * 65536 * 2;
    const size_t SKV  = (size_t)NN * 512 * 2;
    const size_t SAT  = (size_t)NN * DM * 2;
    const size_t SCNT = (size_t)NN * 4;
    const size_t SBK  = (size_t)NN * CAP * 4;
    const size_t need = SWT + SKV + SAT + SCNT + SBK;
    if (ws_size < need) {
        k_fill_zero_f32<<<(out_size + 255) / 256, 256, 0, stream>>>((float*)d_out, out_size);
        return;
    }
    char* p = (char*)d_ws;
    u16* Wt   = (u16*)p; p += SWT;
    u16* KVb  = (u16*)p; p += SKV;
    u16* attn = (u16*)p; p += SAT;
    int* cnt  = (int*)p; p += SCNT;
    int* buck = (int*)p; p += SBK;
    u16* Qb = (u16*)d_out;  // Q staged in d_out lower half (dead before k_gemm_out_ln writes)

    k_prep<<<1024, 256, 0, stream>>>(Wq, Wk, Wv, Wo, Wt, cnt);
    k_qkv_bucket<<<dim3(625, 4), 256, 0, stream>>>(X, Wt, Qb, KVb, EI, cnt, buck);
    k_edge<<<NN / 4, 256, 0, stream>>>(Qb, KVb, cnt, buck, attn);
    k_gemm_out_ln<<<157, 256, 0, stream>>>(attn, Wt + 3 * 65536, X, g, be, (float*)d_out);
}